// Round 2
// baseline (1116.553 us; speedup 1.0000x reference)
//
#include <hip/hip_runtime.h>
#include <math.h>

#define BSZ 8
#define LEN 3072
#define DM 1024
#define TOPK 8

typedef __attribute__((ext_vector_type(8))) short short8;
typedef __attribute__((ext_vector_type(4))) float f32x4;

__device__ __forceinline__ unsigned short f2bf(float x) {
    unsigned int u = __builtin_bit_cast(unsigned int, x);
    u += 0x7fffu + ((u >> 16) & 1u);   // RNE
    return (unsigned short)(u >> 16);
}
__device__ __forceinline__ float bf2f(unsigned short h) {
    unsigned int u = ((unsigned int)h) << 16;
    return __builtin_bit_cast(float, u);
}
__device__ __forceinline__ void gl_lds16(const void* g, void* l) {
    __builtin_amdgcn_global_load_lds(
        (const __attribute__((address_space(1))) unsigned int*)g,
        (__attribute__((address_space(3))) unsigned int*)l, 16, 0, 0);
}

// ---------------------------------------------------------------------------
// f32 tiled GEMM, split-K x4 (1024^3 Amat = Wk @ WqT). grid (8,8,4); each z
// slice writes a partial 1024x1024 buffer; reduce4_f32 sums them.
// ---------------------------------------------------------------------------
#define GBM 128
#define GBN 128
#define GBK 16

__global__ __launch_bounds__(256) void gemm_f32_sk(const float* __restrict__ A,
    const float* __restrict__ B, float* __restrict__ P, int M, int N, int K)
{
    __shared__ float As[GBK][GBM];
    __shared__ float Bs[GBK][GBN];
    const int tid = threadIdx.x;
    const int tx = tid & 15, ty = tid >> 4;
    const size_t m0 = (size_t)blockIdx.y * GBM;
    const size_t n0 = (size_t)blockIdx.x * GBN;
    const int ksl = K >> 2;
    const int kb = blockIdx.z * ksl, ke = kb + ksl;
    const int arow = tid >> 2, acol = (tid & 3) << 2;
    const int brow = tid >> 5, bcol = (tid & 31) << 2;

    float acc[8][8];
#pragma unroll
    for (int i = 0; i < 8; i++)
#pragma unroll
        for (int j = 0; j < 8; j++) acc[i][j] = 0.f;

    const float* Ap0 = A + (m0 + arow) * (size_t)K + acol;
    const float* Ap1 = A + (m0 + arow + 64) * (size_t)K + acol;
    const float* Bp0 = B + (size_t)brow * N + n0 + bcol;
    const float* Bp1 = B + (size_t)(brow + 8) * N + n0 + bcol;

    for (int k0 = kb; k0 < ke; k0 += GBK) {
        float4 a0 = *(const float4*)(Ap0 + k0);
        float4 a1 = *(const float4*)(Ap1 + k0);
        float4 b0 = *(const float4*)(Bp0 + (size_t)k0 * N);
        float4 b1 = *(const float4*)(Bp1 + (size_t)k0 * N);
        __syncthreads();
        As[acol + 0][arow] = a0.x; As[acol + 1][arow] = a0.y;
        As[acol + 2][arow] = a0.z; As[acol + 3][arow] = a0.w;
        As[acol + 0][arow + 64] = a1.x; As[acol + 1][arow + 64] = a1.y;
        As[acol + 2][arow + 64] = a1.z; As[acol + 3][arow + 64] = a1.w;
        *(float4*)&Bs[brow][bcol] = b0;
        *(float4*)&Bs[brow + 8][bcol] = b1;
        __syncthreads();
#pragma unroll
        for (int kk = 0; kk < GBK; kk++) {
            float av[8], bv[8];
            *(float4*)&av[0] = *(const float4*)&As[kk][ty * 8];
            *(float4*)&av[4] = *(const float4*)&As[kk][ty * 8 + 4];
            *(float4*)&bv[0] = *(const float4*)&Bs[kk][tx * 8];
            *(float4*)&bv[4] = *(const float4*)&Bs[kk][tx * 8 + 4];
#pragma unroll
            for (int i = 0; i < 8; i++)
#pragma unroll
                for (int j = 0; j < 8; j++)
                    acc[i][j] = fmaf(av[i], bv[j], acc[i][j]);
        }
    }
    float* Pz = P + (size_t)blockIdx.z * M * N;
#pragma unroll
    for (int i = 0; i < 8; i++) {
        size_t row = m0 + (size_t)(ty * 8 + i);
        float* Cp = Pz + row * N + n0 + tx * 8;
#pragma unroll
        for (int j = 0; j < 8; j++) Cp[j] = acc[i][j];
    }
}

// C[i] = P0[i]+P1[i]+P2[i]+P3[i], float4-wide, n multiple of 4
__global__ __launch_bounds__(256) void reduce4_f32(const float* __restrict__ P,
                                                   float* __restrict__ C, int n)
{
    int i = (blockIdx.x * 256 + threadIdx.x) * 4;
    if (i >= n) return;
    float4 a = *(const float4*)(P + i);
    float4 b = *(const float4*)(P + (size_t)n + i);
    float4 c = *(const float4*)(P + 2 * (size_t)n + i);
    float4 d = *(const float4*)(P + 3 * (size_t)n + i);
    float4 o = {a.x + b.x + c.x + d.x, a.y + b.y + c.y + d.y,
                a.z + b.z + c.z + d.z, a.w + b.w + c.w + d.w};
    *(float4*)(C + i) = o;
}

// XCD-aware bijective block swizzle (requires nwg % 8 == 0, else identity):
// consecutive dispatch ids (same XCD via %8 round-robin) get contiguous tile
// ranges -> row-panel A-tiles reused within one XCD L2.
__device__ __forceinline__ void xcd_tile(int& bx, int& by) {
    int nbx = gridDim.x, nby = gridDim.y;
    int nwg = nbx * nby;
    int flat = by * nbx + bx;
    if (!(nwg & 7)) {
        int sw = (flat & 7) * (nwg >> 3) + (flat >> 3);
        bx = sw % nbx;
        by = sw / nbx;
    }
}

// ---------------------------------------------------------------------------
// Split-bf16 MFMA GEMM for the selection-critical z path:
//   z = keys @ Amat + bz, computed as Khi@Ahi + Khi@Alo + Klo@Ahi
// (each split half bf16; ~17 effective mantissa bits; lo*lo term ~2^-18 dropped).
// Writes OUTPUT TRANSPOSED: zT[b][c][t], m = b*LEN + t.
// 128x128 tile, BK=32, 256 thr (2x2 waves), 16x16x32 MFMA, global_load_lds x16.
// ---------------------------------------------------------------------------
__global__ __launch_bounds__(256) void gemm_split_zT(
    const unsigned short* __restrict__ Khi, const unsigned short* __restrict__ Klo,
    const unsigned short* __restrict__ AhiT, const unsigned short* __restrict__ AloT,
    const float* __restrict__ bias, float* __restrict__ zT, int M, int N, int K)
{
    __shared__ unsigned short Ah[128 * 32];
    __shared__ unsigned short Al[128 * 32];
    __shared__ unsigned short Bh[128 * 32];
    __shared__ unsigned short Bl[128 * 32];
    const int tid = threadIdx.x;
    const int lane = tid & 63;
    const int wv = tid >> 6;
    const int wm = wv >> 1, wn = wv & 1;
    const int l16 = lane & 15, quad = lane >> 4;
    int bx = blockIdx.x, by = blockIdx.y;
    xcd_tile(bx, by);
    const size_t m0 = (size_t)by * 128;
    const size_t n0 = (size_t)bx * 128;

    const int s0 = tid, s1 = tid + 256;       // segment: row = s>>2, col8 = s&3
    const size_t oA0 = (m0 + (s0 >> 2)) * (size_t)K + (s0 & 3) * 8;
    const size_t oA1 = (m0 + (s1 >> 2)) * (size_t)K + (s1 & 3) * 8;
    const size_t oB0 = (n0 + (s0 >> 2)) * (size_t)K + (s0 & 3) * 8;
    const size_t oB1 = (n0 + (s1 >> 2)) * (size_t)K + (s1 & 3) * 8;

    f32x4 acc[4][4];
#pragma unroll
    for (int i = 0; i < 4; i++)
#pragma unroll
        for (int j = 0; j < 4; j++) acc[i][j] = (f32x4){0.f, 0.f, 0.f, 0.f};

    for (int k0 = 0; k0 < K; k0 += 32) {
        __syncthreads();
        gl_lds16(Khi + oA0 + k0, &Ah[s0 * 8]);
        gl_lds16(Khi + oA1 + k0, &Ah[s1 * 8]);
        gl_lds16(Klo + oA0 + k0, &Al[s0 * 8]);
        gl_lds16(Klo + oA1 + k0, &Al[s1 * 8]);
        gl_lds16(AhiT + oB0 + k0, &Bh[s0 * 8]);
        gl_lds16(AhiT + oB1 + k0, &Bh[s1 * 8]);
        gl_lds16(AloT + oB0 + k0, &Bl[s0 * 8]);
        gl_lds16(AloT + oB1 + k0, &Bl[s1 * 8]);
        __syncthreads();
        short8 ah[4], al[4], bh[4], bl[4];
#pragma unroll
        for (int mi = 0; mi < 4; mi++) {
            int off = (wm * 64 + mi * 16 + l16) * 32 + quad * 8;
            ah[mi] = *(const short8*)&Ah[off];
            al[mi] = *(const short8*)&Al[off];
        }
#pragma unroll
        for (int ni = 0; ni < 4; ni++) {
            int off = (wn * 64 + ni * 16 + l16) * 32 + quad * 8;
            bh[ni] = *(const short8*)&Bh[off];
            bl[ni] = *(const short8*)&Bl[off];
        }
#pragma unroll
        for (int mi = 0; mi < 4; mi++)
#pragma unroll
            for (int ni = 0; ni < 4; ni++) {
                acc[mi][ni] = __builtin_amdgcn_mfma_f32_16x16x32_bf16(
                    ah[mi], bh[ni], acc[mi][ni], 0, 0, 0);
                acc[mi][ni] = __builtin_amdgcn_mfma_f32_16x16x32_bf16(
                    ah[mi], bl[ni], acc[mi][ni], 0, 0, 0);
                acc[mi][ni] = __builtin_amdgcn_mfma_f32_16x16x32_bf16(
                    al[mi], bh[ni], acc[mi][ni], 0, 0, 0);
            }
    }

    const int b = (int)(m0 / LEN);
    const int t0 = (int)(m0 % LEN);
#pragma unroll
    for (int mi = 0; mi < 4; mi++) {
#pragma unroll
        for (int ni = 0; ni < 4; ni++) {
            int c = (int)n0 + wn * 64 + ni * 16 + l16;
            int t = t0 + wm * 64 + mi * 16 + quad * 4;
            float bb = bias[c];
            float* zp = zT + ((size_t)b * DM + c) * LEN + t;
#pragma unroll
            for (int r = 0; r < 4; r++) zp[r] = acc[mi][ni][r] + bb;
        }
    }
}

// ---------------------------------------------------------------------------
// bf16 MFMA GEMM (m97 structure): C[M,N] = A[M,K] * Bt[N,K]^T + bias.
// cmode: 0 -> f32 C, 1 -> bf16 C.
// ---------------------------------------------------------------------------
__global__ __launch_bounds__(256) void gemm_bf16(const unsigned short* __restrict__ A,
    const unsigned short* __restrict__ Bt, const float* __restrict__ bias,
    void* __restrict__ C, int M, int N, int K, int cmode)
{
    __shared__ unsigned short As[128 * 32];
    __shared__ unsigned short Bs[128 * 32];
    const int tid = threadIdx.x;
    const int lane = tid & 63;
    const int wv = tid >> 6;
    const int wm = wv >> 1, wn = wv & 1;
    const int l16 = lane & 15, quad = lane >> 4;
    int bx = blockIdx.x, by = blockIdx.y;
    xcd_tile(bx, by);
    const size_t m0 = (size_t)by * 128;
    const size_t n0 = (size_t)bx * 128;

    const int s0 = tid, s1 = tid + 256;
    const unsigned short* gA0 = A + (m0 + (s0 >> 2)) * (size_t)K + (s0 & 3) * 8;
    const unsigned short* gA1 = A + (m0 + (s1 >> 2)) * (size_t)K + (s1 & 3) * 8;
    const unsigned short* gB0 = Bt + (n0 + (s0 >> 2)) * (size_t)K + (s0 & 3) * 8;
    const unsigned short* gB1 = Bt + (n0 + (s1 >> 2)) * (size_t)K + (s1 & 3) * 8;
    unsigned short* lA0 = &As[s0 * 8];
    unsigned short* lA1 = &As[s1 * 8];
    unsigned short* lB0 = &Bs[s0 * 8];
    unsigned short* lB1 = &Bs[s1 * 8];

    f32x4 acc[4][4];
#pragma unroll
    for (int i = 0; i < 4; i++)
#pragma unroll
        for (int j = 0; j < 4; j++) acc[i][j] = (f32x4){0.f, 0.f, 0.f, 0.f};

    for (int k0 = 0; k0 < K; k0 += 32) {
        __syncthreads();
        gl_lds16(gA0 + k0, lA0);
        gl_lds16(gA1 + k0, lA1);
        gl_lds16(gB0 + k0, lB0);
        gl_lds16(gB1 + k0, lB1);
        __syncthreads();
        short8 af[4], bf[4];
#pragma unroll
        for (int mi = 0; mi < 4; mi++)
            af[mi] = *(const short8*)&As[(wm * 64 + mi * 16 + l16) * 32 + quad * 8];
#pragma unroll
        for (int ni = 0; ni < 4; ni++)
            bf[ni] = *(const short8*)&Bs[(wn * 64 + ni * 16 + l16) * 32 + quad * 8];
#pragma unroll
        for (int mi = 0; mi < 4; mi++)
#pragma unroll
            for (int ni = 0; ni < 4; ni++)
                acc[mi][ni] = __builtin_amdgcn_mfma_f32_16x16x32_bf16(
                    af[mi], bf[ni], acc[mi][ni], 0, 0, 0);
    }

#pragma unroll
    for (int mi = 0; mi < 4; mi++) {
#pragma unroll
        for (int ni = 0; ni < 4; ni++) {
            int gm = (int)m0 + wm * 64 + mi * 16 + quad * 4;
            int gn = (int)n0 + wn * 64 + ni * 16 + l16;
            float bb = bias ? bias[gn] : 0.f;
#pragma unroll
            for (int r = 0; r < 4; r++) {
                float v = acc[mi][ni][r] + bb;
                if (cmode == 0)
                    ((float*)C)[(size_t)(gm + r) * N + gn] = v;
                else
                    ((unsigned short*)C)[(size_t)(gm + r) * N + gn] = f2bf(v);
            }
        }
    }
}

// ---------------------------------------------------------------------------
// [B, L, D] f32 -> [B, D, L] f32 transpose (queries)
// ---------------------------------------------------------------------------
__global__ __launch_bounds__(256) void transpose_bld(const float* __restrict__ in,
                                                     float* __restrict__ out)
{
    __shared__ float tile[32][33];
    int b = blockIdx.z;
    int d0 = blockIdx.x * 32, t0 = blockIdx.y * 32;
    int tx = threadIdx.x & 31, ty = threadIdx.x >> 5;
    const float* ip = in + (size_t)b * LEN * DM;
    float* op = out + (size_t)b * DM * LEN;
#pragma unroll
    for (int r = 0; r < 4; r++)
        tile[ty * 4 + r][tx] = ip[(size_t)(t0 + ty * 4 + r) * DM + d0 + tx];
    __syncthreads();
#pragma unroll
    for (int r = 0; r < 4; r++)
        op[(size_t)(d0 + ty * 4 + r) * LEN + t0 + tx] = tile[tx][ty * 4 + r];
}

// 1024x1024 f32 transpose (Wq -> WqT)
__global__ __launch_bounds__(256) void transpose_1024(const float* __restrict__ in,
                                                      float* __restrict__ out)
{
    __shared__ float tile[32][33];
    int bx = blockIdx.x & 31, by = blockIdx.x >> 5;
    int tx = threadIdx.x & 31, tq = threadIdx.x >> 5;
#pragma unroll
    for (int r = 0; r < 4; r++)
        tile[tq * 4 + r][tx] = in[(size_t)(by * 32 + tq * 4 + r) * 1024 + bx * 32 + tx];
    __syncthreads();
#pragma unroll
    for (int r = 0; r < 4; r++)
        out[(size_t)(bx * 32 + tq * 4 + r) * 1024 + by * 32 + tx] = tile[tx][tq * 4 + r];
}

// 1024x1024 f32 W[K][N] -> bf16 WT[N][K]
__global__ __launch_bounds__(256) void transpose_w_bf16(const float* __restrict__ in,
                                                        unsigned short* __restrict__ out)
{
    __shared__ float tile[32][33];
    int bx = blockIdx.x & 31, by = blockIdx.x >> 5;
    int tx = threadIdx.x & 31, tq = threadIdx.x >> 5;
#pragma unroll
    for (int r = 0; r < 4; r++)
        tile[tq * 4 + r][tx] = in[(size_t)(by * 32 + tq * 4 + r) * 1024 + bx * 32 + tx];
    __syncthreads();
#pragma unroll
    for (int r = 0; r < 4; r++)
        out[(size_t)(bx * 32 + tq * 4 + r) * 1024 + by * 32 + tx] = f2bf(tile[tx][tq * 4 + r]);
}

// 1024x1024 f32 W[K][N] -> split bf16 hi/lo, transposed [N][K]
__global__ __launch_bounds__(256) void transpose_w_split(const float* __restrict__ in,
    unsigned short* __restrict__ hi, unsigned short* __restrict__ lo)
{
    __shared__ float tile[32][33];
    int bx = blockIdx.x & 31, by = blockIdx.x >> 5;
    int tx = threadIdx.x & 31, tq = threadIdx.x >> 5;
#pragma unroll
    for (int r = 0; r < 4; r++)
        tile[tq * 4 + r][tx] = in[(size_t)(by * 32 + tq * 4 + r) * 1024 + bx * 32 + tx];
    __syncthreads();
#pragma unroll
    for (int r = 0; r < 4; r++) {
        float x = tile[tx][tq * 4 + r];
        unsigned short h = f2bf(x);
        unsigned short l = f2bf(x - bf2f(h));
        size_t o = (size_t)(bx * 32 + tq * 4 + r) * 1024 + by * 32 + tx;
        hi[o] = h; lo[o] = l;
    }
}

// f32 -> split bf16 hi/lo elementwise (n multiple of 4)
__global__ __launch_bounds__(256) void split_bf16(const float* __restrict__ in,
    unsigned short* __restrict__ hi, unsigned short* __restrict__ lo, size_t n)
{
    size_t i = ((size_t)blockIdx.x * 256 + threadIdx.x) * 4;
    if (i >= n) return;
    float4 v = *(const float4*)(in + i);
    ushort4 h, l;
    h.x = f2bf(v.x); l.x = f2bf(v.x - bf2f(h.x));
    h.y = f2bf(v.y); l.y = f2bf(v.y - bf2f(h.y));
    h.z = f2bf(v.z); l.z = f2bf(v.z - bf2f(h.z));
    h.w = f2bf(v.w); l.w = f2bf(v.w - bf2f(h.w));
    *(ushort4*)(hi + i) = h;
    *(ushort4*)(lo + i) = l;
}

// f32 -> bf16 elementwise (n multiple of 4)
__global__ __launch_bounds__(256) void conv_bf16(const float* __restrict__ in,
                                                 unsigned short* __restrict__ out, size_t n)
{
    size_t i = ((size_t)blockIdx.x * 256 + threadIdx.x) * 4;
    if (i >= n) return;
    float4 v = *(const float4*)(in + i);
    ushort4 o;
    o.x = f2bf(v.x); o.y = f2bf(v.y); o.z = f2bf(v.z); o.w = f2bf(v.w);
    *(ushort4*)(out + i) = o;
}

// bz[j] = sum_d bk[d] * WqT[d,j]
__global__ __launch_bounds__(256) void bz_kernel(const float* __restrict__ bk,
    const float* __restrict__ WqT, float* __restrict__ bz)
{
    int j = blockIdx.x * 256 + threadIdx.x;
    float s = 0.f;
    for (int d = 0; d < 1024; d++) s = fmaf(bk[d], WqT[(size_t)d * 1024 + j], s);
    bz[j] = s;
}

__global__ void zero_f32(float* __restrict__ p, int n)
{
    int i = blockIdx.x * 256 + threadIdx.x;
    if (i < n) p[i] = 0.f;
}

// ---------------------------------------------------------------------------
// 3072-point complex FFT in LDS, fused radix-4 Stockham (5 double-stages) on
// 3x1024 sub-FFTs + radix-3 combine. Interleaved float2 storage (b64 LDS ops),
// XOR bank swizzle swz(i) = i ^ ((i>>4)&15).
// ALL twiddles live in per-thread REGISTERS (they depend only on tid):
//   stage si (s=2*si): wA = e^{-2pi i ((tid>>s)<<s)/1024}, w2 = wA^2 (exact:
//   tw[p<<(s+1)] = tw[p<<s]^2), radix-3: w1_j = e^{-2pi i (tid+256j)/3072},
//   w2c_j = w1_j^2.  -> LDS = bufA+bufB only (48 KiB) -> 3 blocks/CU.
// Result ends in bufA.
// ---------------------------------------------------------------------------
__device__ __forceinline__ int swz(int i) { return i ^ ((i >> 4) & 15); }

__device__ __forceinline__ float2 cmul(float2 a, float2 b) {
    return make_float2(a.x * b.x - a.y * b.y, a.x * b.y + a.y * b.x);
}

struct TwRegs {
    float2 wA[5], w2[5], w1[4], w2c[4];
};

__device__ __forceinline__ void make_tw(TwRegs& T, int tid)
{
    const float TWO_PI = 6.28318530717958647692f;
#pragma unroll
    for (int si = 0; si < 5; si++) {
        int s = si * 2;
        int a = (tid >> s) << s;
        float sv, cv; sincosf(-TWO_PI * (float)a / 1024.f, &sv, &cv);
        T.wA[si] = make_float2(cv, sv);
        T.w2[si] = make_float2(cv * cv - sv * sv, 2.f * cv * sv);
    }
#pragma unroll
    for (int j = 0; j < 4; j++) {
        int k2 = tid + (j << 8);
        float sv, cv; sincosf(-TWO_PI * (float)k2 / 3072.f, &sv, &cv);
        T.w1[j] = make_float2(cv, sv);
        T.w2c[j] = make_float2(cv * cv - sv * sv, 2.f * cv * sv);
    }
}

__device__ __forceinline__ void fft3072_r4(float2* __restrict__ bufA,
                                           float2* __restrict__ bufB,
                                           const TwRegs& T, int tid)
{
    float2* src = bufA;
    float2* dst = bufB;
#pragma unroll
    for (int s = 0; s < 10; s += 2) {
        const int st = 1 << s;
        const int q = tid & (st - 1);
        const int p = tid >> s;
        const float2 wA = T.wA[s >> 1];
        const float2 w2 = T.w2[s >> 1];
        const int io = q + (p << (s + 2));
#pragma unroll
        for (int k = 0; k < 3; k++) {
            const int base = k << 10;
            float2 a1 = src[swz(base + tid)];
            float2 a2 = src[swz(base + tid + 256)];
            float2 b1 = src[swz(base + tid + 512)];
            float2 b2 = src[swz(base + tid + 768)];
            float2 uA0 = make_float2(a1.x + b1.x, a1.y + b1.y);
            float2 d1  = make_float2(a1.x - b1.x, a1.y - b1.y);
            float2 uA1 = cmul(d1, wA);
            float2 uB0 = make_float2(a2.x + b2.x, a2.y + b2.y);
            float2 d2  = make_float2(a2.x - b2.x, a2.y - b2.y);
            float2 e   = cmul(d2, wA);
            float2 uB1 = make_float2(e.y, -e.x);          // e * (-i)
            float2 o0 = make_float2(uA0.x + uB0.x, uA0.y + uB0.y);
            float2 o1 = make_float2(uA1.x + uB1.x, uA1.y + uB1.y);
            float2 e2 = make_float2(uA0.x - uB0.x, uA0.y - uB0.y);
            float2 e3 = make_float2(uA1.x - uB1.x, uA1.y - uB1.y);
            dst[swz(base + io)] = o0;
            dst[swz(base + io + st)] = o1;
            dst[swz(base + io + 2 * st)] = cmul(e2, w2);
            dst[swz(base + io + 3 * st)] = cmul(e3, w2);
        }
        __syncthreads();
        float2* t = src; src = dst; dst = t;
    }
    // radix-3 combine: src == bufB here, dst == bufA
    const float OMR = -0.5f, OMI = -0.86602540378443864676f;
#pragma unroll
    for (int j = 0; j < 4; j++) {
        int k2 = tid + (j << 8);
        float2 y0 = src[swz(k2)];
        float2 y1 = src[swz(1024 + k2)];
        float2 y2 = src[swz(2048 + k2)];
        float2 w1 = T.w1[j];
        float2 w2c = T.w2c[j];
        float2 u1 = cmul(y1, w1);
        float2 u2 = cmul(y2, w2c);
        dst[swz(k2)] = make_float2(y0.x + u1.x + u2.x, y0.y + u1.y + u2.y);
        dst[swz(1024 + k2)] = make_float2(
            y0.x + (OMR * u1.x - OMI * u1.y) + (OMR * u2.x + OMI * u2.y),
            y0.y + (OMR * u1.y + OMI * u1.x) + (OMR * u2.y - OMI * u2.x));
        dst[swz(2048 + k2)] = make_float2(
            y0.x + (OMR * u1.x + OMI * u1.y) + (OMR * u2.x - OMI * u2.y),
            y0.y + (OMR * u1.y - OMI * u1.x) + (OMR * u2.y + OMI * u2.x));
    }
    __syncthreads();
}

// ---------------------------------------------------------------------------
// Per (batch, 8-channel group): inputs channel-major [B, D, L] (coalesced).
// Pack w = q + i*z, FFT, P[f] = Qf * conj(Zf). q,z real => S is Hermitian,
// so accumulate only f in [0,1536] (halves accum work + atomics).
// grid = BSZ*128 blocks; 48 KiB LDS -> 3 blocks/CU.
// ---------------------------------------------------------------------------
__global__ __launch_bounds__(256, 3) void fft_corr(const float* __restrict__ qT,
    const float* __restrict__ zT, float* __restrict__ S)
{
    __shared__ float2 bufA[3072], bufB[3072];
    const int tid = threadIdx.x;
    const int b = blockIdx.x >> 7;
    const int c0 = (blockIdx.x & 127) << 3;
    TwRegs T;
    make_tw(T, tid);
    float pR[6], pI[6];
#pragma unroll
    for (int j = 0; j < 6; j++) { pR[j] = 0.f; pI[j] = 0.f; }
    float eR = 0.f, eI = 0.f;   // f = 1536 (tid 0 only)

    for (int ci = 0; ci < 8; ci++) {
        int c = c0 + ci;
        const float* qp = qT + ((size_t)b * DM + c) * LEN;
        const float* zp = zT + ((size_t)b * DM + c) * LEN;
        for (int t = tid; t < 3072; t += 256) {
            float qv = qp[t];
            float zv = zp[t];
            int t1 = t % 3, t2 = t / 3;
            bufA[swz(t1 * 1024 + t2)] = make_float2(qv, zv);
        }
        __syncthreads();
        fft3072_r4(bufA, bufB, T, tid);
        // result in bufA; accumulate f in [0,1535] + special f=1536
#pragma unroll
        for (int j = 0; j < 6; j++) {
            int f = tid + (j << 8);
            int fc = (f == 0) ? 0 : 3072 - f;
            float2 Wf = bufA[swz(f)];
            float2 Wc = bufA[swz(fc)];
            float WcI = -Wc.y;
            float qR = 0.5f * (Wf.x + Wc.x), qI = 0.5f * (Wf.y + WcI);
            float dR = Wf.x - Wc.x, dI = Wf.y - WcI;
            float zR = 0.5f * dI, zI = -0.5f * dR;
            pR[j] += qR * zR + qI * zI;
            pI[j] += qI * zR - qR * zI;
        }
        if (tid == 0) {
            float2 Wf = bufA[swz(1536)];   // self-conjugate bin
            float qR = Wf.x, qI = 0.f;
            float dI = 2.f * Wf.y;
            float zR = 0.5f * dI, zI = 0.f;
            eR += qR * zR + qI * zI;
            eI += qI * zR - qR * zI;
        }
        __syncthreads();
    }
    float* Sb = S + (size_t)b * 3072 * 2;
#pragma unroll
    for (int j = 0; j < 6; j++) {
        int f = tid + (j << 8);
        atomicAdd(&Sb[f * 2 + 0], pR[j]);
        atomicAdd(&Sb[f * 2 + 1], pI[j]);
    }
    if (tid == 0) {
        atomicAdd(&Sb[1536 * 2 + 0], eR);
        atomicAdd(&Sb[1536 * 2 + 1], eI);
    }
}

__global__ __launch_bounds__(256) void ifft_mean(const float* __restrict__ S,
                                                 float* __restrict__ mv)
{
    __shared__ float2 bufA[3072], bufB[3072];
    const int tid = threadIdx.x;
    const int b = blockIdx.x;
    TwRegs T;
    make_tw(T, tid);
    // S stored only for f in [0,1536]; reconstruct f>1536 via S_{-f}=conj(S_f).
    for (int t = tid; t < 3072; t += 256) {
        int tt = (t <= 1536) ? t : 3072 - t;
        float sR = S[((size_t)b * 3072 + tt) * 2 + 0];
        float sI = S[((size_t)b * 3072 + tt) * 2 + 1];
        float im = (t > 1536) ? sI : -sI;   // conj-pack for inverse FFT
        int t1 = t % 3, t2 = t / 3;
        bufA[swz(t1 * 1024 + t2)] = make_float2(sR, im);
    }
    __syncthreads();
    fft3072_r4(bufA, bufB, T, tid);
    const float scale = 1.f / (3072.f * 1024.f);
    for (int t = tid; t < 3072; t += 256)
        mv[(size_t)b * 3072 + t] = bufA[swz(t)].x * scale;
}

__global__ __launch_bounds__(256) void topk_softmax(const float* __restrict__ mv,
    float* __restrict__ wout, int* __restrict__ dout)
{
    const int b = blockIdx.x, tid = threadIdx.x;
    __shared__ float v[3072];
    __shared__ float rv[256];
    __shared__ int   ri[256];
    __shared__ float topv[TOPK];
    __shared__ int   topi[TOPK];
    for (int t = tid; t < 3072; t += 256) v[t] = mv[(size_t)b * 3072 + t];
    __syncthreads();
    for (int it = 0; it < TOPK; it++) {
        float best = -3.0e38f; int bi = 0;
        for (int t = tid; t < 3072; t += 256) {
            float x = v[t];
            if (x > best) { best = x; bi = t; }
        }
        rv[tid] = best; ri[tid] = bi;
        __syncthreads();
        for (int off = 128; off > 0; off >>= 1) {
            if (tid < off) {
                float ov = rv[tid + off]; int oi = ri[tid + off];
                if (ov > rv[tid] || (ov == rv[tid] && oi < ri[tid])) {
                    rv[tid] = ov; ri[tid] = oi;
                }
            }
            __syncthreads();
        }
        if (tid == 0) { topv[it] = rv[0]; topi[it] = ri[0]; v[ri[0]] = -3.0e38f; }
        __syncthreads();
    }
    if (tid == 0) {
        float m = topv[0];
        float e[TOPK]; float ssum = 0.f;
        for (int i = 0; i < TOPK; i++) { e[i] = expf(topv[i] - m); ssum += e[i]; }
        for (int i = 0; i < TOPK; i++) {
            wout[b * TOPK + i] = e[i] / ssum;
            dout[b * TOPK + i] = topi[i];
        }
    }
}

// agg[b,t,c] = sum_i w[b,i] * V[b,(t+d[b,i])%L,c]   (bf16 in, bf16 out)
__global__ __launch_bounds__(256) void agg_bf16(const unsigned short* __restrict__ V,
    const float* __restrict__ w, const int* __restrict__ d,
    unsigned short* __restrict__ agg)
{
    size_t gid = (size_t)blockIdx.x * 256 + threadIdx.x;   // 8-channel chunk index
    int c8 = (int)(gid & 127);
    size_t rest = gid >> 7;
    int t = (int)(rest % LEN);
    int b = (int)(rest / LEN);
    float acc[8];
#pragma unroll
    for (int j = 0; j < 8; j++) acc[j] = 0.f;
#pragma unroll
    for (int i = 0; i < TOPK; i++) {
        float wi = w[b * TOPK + i];
        int r = t + d[b * TOPK + i];
        if (r >= LEN) r -= LEN;
        const unsigned short* vp = V + ((size_t)b * LEN + r) * DM + c8 * 8;
        uint4 raw = *(const uint4*)vp;
        unsigned int uu[4] = {raw.x, raw.y, raw.z, raw.w};
#pragma unroll
        for (int k = 0; k < 4; k++) {
            acc[2 * k]     = fmaf(wi, bf2f((unsigned short)(uu[k] & 0xffff)), acc[2 * k]);
            acc[2 * k + 1] = fmaf(wi, bf2f((unsigned short)(uu[k] >> 16)), acc[2 * k + 1]);
        }
    }
    unsigned int ou[4];
#pragma unroll
    for (int k = 0; k < 4; k++)
        ou[k] = (unsigned int)f2bf(acc[2 * k]) | ((unsigned int)f2bf(acc[2 * k + 1]) << 16);
    uint4 o = {ou[0], ou[1], ou[2], ou[3]};
    *(uint4*)(agg + gid * 8) = o;
}

// ---------------------------------------------------------------------------
extern "C" void kernel_launch(void* const* d_in, const int* in_sizes, int n_in,
                              void* d_out, int out_size, void* d_ws, size_t ws_size,
                              hipStream_t stream)
{
    const float* queries = (const float*)d_in[0];
    const float* keys    = (const float*)d_in[1];
    const float* values  = (const float*)d_in[2];
    const float* Wq = (const float*)d_in[3];
    // bq: tau-constant in mean_value -> topk/softmax invariant; legally dropped
    const float* Wk = (const float*)d_in[5];
    const float* bk = (const float*)d_in[6];
    const float* Wv = (const float*)d_in[7];
    const float* bv = (const float*)d_in[8];
    const float* Wo = (const float*)d_in[9];
    const float* bo = (const float*)d_in[10];
    float* out = (float*)d_out;

    char* ws = (char*)d_ws;
    size_t off = 0;
    auto alloc = [&](size_t bytes) -> char* {
        char* p = ws + off;
        off += (bytes + 255) & ~(size_t)255;
        return p;
    };
    const size_t BLD = (size_t)BSZ * LEN * DM;          // 25165824 elements
    float* WqT  = (float*)alloc((size_t)1024 * 1024 * 4);
    float* Amat = (float*)alloc((size_t)1024 * 1024 * 4);
    unsigned short* AhiT = (unsigned short*)alloc((size_t)1024 * 1024 * 2);
    unsigned short* AloT = (unsigned short*)alloc((size_t)1024 * 1024 * 2);
    float* bz   = (float*)alloc(1024 * 4);
    float* S    = (float*)alloc((size_t)BSZ * 3072 * 2 * 4);
    float* mv   = (float*)alloc((size_t)BSZ * 3072 * 4);
    float* wsm  = (float*)alloc(BSZ * TOPK * 4);
    int*   dly  = (int*)alloc(BSZ * TOPK * 4);
    unsigned short* WvT = (unsigned short*)alloc((size_t)1024 * 1024 * 2);
    unsigned short* WoT = (unsigned short*)alloc((size_t)1024 * 1024 * 2);
    // two big regions, phase-aliased:
    //   bigA: ph0: khi+klo (bf16) | ph1: qT f32 | ph2: vb16 + aggb (bf16)
    //   bigB: ph-1: Amat split-K partials (4x4MB) | ph1: zT f32 | ph2: Vb bf16
    char* bigA = alloc(BLD * 4);
    char* bigB = alloc(BLD * 4);
    unsigned short* khi = (unsigned short*)bigA;
    unsigned short* klo = (unsigned short*)(bigA + BLD * 2);
    float* qT = (float*)bigA;
    float* zT = (float*)bigB;
    float* Apart = (float*)bigB;            // 4 x 1024^2 f32 partials (16 MB)
    unsigned short* vb16 = (unsigned short*)bigA;
    unsigned short* aggb = (unsigned short*)(bigA + BLD * 2);
    unsigned short* Vb   = (unsigned short*)bigB;

    const int BL = BSZ * LEN; // 24576

    // ---- selection path (split-bf16 MFMA; ~17 mantissa bits) ----
    transpose_1024<<<1024, 256, 0, stream>>>(Wq, WqT);
    gemm_f32_sk<<<dim3(8, 8, 4), 256, 0, stream>>>(Wk, WqT, Apart, 1024, 1024, 1024);
    reduce4_f32<<<1024, 256, 0, stream>>>(Apart, Amat, 1024 * 1024);
    bz_kernel<<<4, 256, 0, stream>>>(bk, WqT, bz);
    transpose_w_split<<<1024, 256, 0, stream>>>(Amat, AhiT, AloT);
    split_bf16<<<(int)((BLD / 4 + 255) / 256), 256, 0, stream>>>(keys, khi, klo, BLD);
    // zT[b][c][t] = (keys @ Amat + bz)^T  via 3-product split-bf16 MFMA
    gemm_split_zT<<<dim3(8, 192), 256, 0, stream>>>(khi, klo, AhiT, AloT, bz, zT,
                                                    BL, 1024, 1024);
    // qT[b][c][t]  (khi/klo dead now; overwrite bigA)
    transpose_bld<<<dim3(32, 96, 8), 256, 0, stream>>>(queries, qT);
    zero_f32<<<(BSZ * 3072 * 2 + 255) / 256, 256, 0, stream>>>(S, BSZ * 3072 * 2);
    fft_corr<<<BSZ * 128, 256, 0, stream>>>(qT, zT, S);
    ifft_mean<<<BSZ, 256, 0, stream>>>(S, mv);
    topk_softmax<<<BSZ, 256, 0, stream>>>(mv, wsm, dly);

    // ---- value path (bf16 MFMA) ----
    conv_bf16<<<(int)((BLD / 4 + 255) / 256), 256, 0, stream>>>(values, vb16, BLD);
    transpose_w_bf16<<<1024, 256, 0, stream>>>(Wv, WvT);
    transpose_w_bf16<<<1024, 256, 0, stream>>>(Wo, WoT);
    gemm_bf16<<<dim3(8, 192), 256, 0, stream>>>(vb16, WvT, bv, Vb, BL, 1024, 1024, 1);
    agg_bf16<<<(int)(((size_t)BL * 128) / 256), 256, 0, stream>>>(Vb, wsm, dly, aggb);
    gemm_bf16<<<dim3(8, 192), 256, 0, stream>>>(aggb, WoT, bo, out, BL, 1024, 1024, 0);
}

// Round 4
// 891.071 us; speedup vs baseline: 1.2530x; 1.2530x over previous
//
#include <hip/hip_runtime.h>
#include <math.h>

#define BSZ 8
#define LEN 3072
#define DM 1024
#define TOPK 8

typedef __attribute__((ext_vector_type(8))) short short8;
typedef __attribute__((ext_vector_type(4))) float f32x4;

__device__ __forceinline__ unsigned short f2bf(float x) {
    unsigned int u = __builtin_bit_cast(unsigned int, x);
    u += 0x7fffu + ((u >> 16) & 1u);   // RNE
    return (unsigned short)(u >> 16);
}
__device__ __forceinline__ float bf2f(unsigned short h) {
    unsigned int u = ((unsigned int)h) << 16;
    return __builtin_bit_cast(float, u);
}
__device__ __forceinline__ void gl_lds16(const void* g, void* l) {
    __builtin_amdgcn_global_load_lds(
        (const __attribute__((address_space(1))) unsigned int*)g,
        (__attribute__((address_space(3))) unsigned int*)l, 16, 0, 0);
}

// ---------------------------------------------------------------------------
// f32 tiled GEMM, split-K x4 (1024^3 Amat = Wk @ WqT). grid (8,8,4); each z
// slice writes a partial 1024x1024 buffer; reduce4_f32 sums them.
// ---------------------------------------------------------------------------
#define GBM 128
#define GBN 128
#define GBK 16

__global__ __launch_bounds__(256) void gemm_f32_sk(const float* __restrict__ A,
    const float* __restrict__ B, float* __restrict__ P, int M, int N, int K)
{
    __shared__ float As[GBK][GBM];
    __shared__ float Bs[GBK][GBN];
    const int tid = threadIdx.x;
    const int tx = tid & 15, ty = tid >> 4;
    const size_t m0 = (size_t)blockIdx.y * GBM;
    const size_t n0 = (size_t)blockIdx.x * GBN;
    const int ksl = K >> 2;
    const int kb = blockIdx.z * ksl, ke = kb + ksl;
    const int arow = tid >> 2, acol = (tid & 3) << 2;
    const int brow = tid >> 5, bcol = (tid & 31) << 2;

    float acc[8][8];
#pragma unroll
    for (int i = 0; i < 8; i++)
#pragma unroll
        for (int j = 0; j < 8; j++) acc[i][j] = 0.f;

    const float* Ap0 = A + (m0 + arow) * (size_t)K + acol;
    const float* Ap1 = A + (m0 + arow + 64) * (size_t)K + acol;
    const float* Bp0 = B + (size_t)brow * N + n0 + bcol;
    const float* Bp1 = B + (size_t)(brow + 8) * N + n0 + bcol;

    for (int k0 = kb; k0 < ke; k0 += GBK) {
        float4 a0 = *(const float4*)(Ap0 + k0);
        float4 a1 = *(const float4*)(Ap1 + k0);
        float4 b0 = *(const float4*)(Bp0 + (size_t)k0 * N);
        float4 b1 = *(const float4*)(Bp1 + (size_t)k0 * N);
        __syncthreads();
        As[acol + 0][arow] = a0.x; As[acol + 1][arow] = a0.y;
        As[acol + 2][arow] = a0.z; As[acol + 3][arow] = a0.w;
        As[acol + 0][arow + 64] = a1.x; As[acol + 1][arow + 64] = a1.y;
        As[acol + 2][arow + 64] = a1.z; As[acol + 3][arow + 64] = a1.w;
        *(float4*)&Bs[brow][bcol] = b0;
        *(float4*)&Bs[brow + 8][bcol] = b1;
        __syncthreads();
#pragma unroll
        for (int kk = 0; kk < GBK; kk++) {
            float av[8], bv[8];
            *(float4*)&av[0] = *(const float4*)&As[kk][ty * 8];
            *(float4*)&av[4] = *(const float4*)&As[kk][ty * 8 + 4];
            *(float4*)&bv[0] = *(const float4*)&Bs[kk][tx * 8];
            *(float4*)&bv[4] = *(const float4*)&Bs[kk][tx * 8 + 4];
#pragma unroll
            for (int i = 0; i < 8; i++)
#pragma unroll
                for (int j = 0; j < 8; j++)
                    acc[i][j] = fmaf(av[i], bv[j], acc[i][j]);
        }
    }
    float* Pz = P + (size_t)blockIdx.z * M * N;
#pragma unroll
    for (int i = 0; i < 8; i++) {
        size_t row = m0 + (size_t)(ty * 8 + i);
        float* Cp = Pz + row * N + n0 + tx * 8;
#pragma unroll
        for (int j = 0; j < 8; j++) Cp[j] = acc[i][j];
    }
}

// C[i] = P0[i]+P1[i]+P2[i]+P3[i], float4-wide, n multiple of 4
__global__ __launch_bounds__(256) void reduce4_f32(const float* __restrict__ P,
                                                   float* __restrict__ C, int n)
{
    int i = (blockIdx.x * 256 + threadIdx.x) * 4;
    if (i >= n) return;
    float4 a = *(const float4*)(P + i);
    float4 b = *(const float4*)(P + (size_t)n + i);
    float4 c = *(const float4*)(P + 2 * (size_t)n + i);
    float4 d = *(const float4*)(P + 3 * (size_t)n + i);
    float4 o = {a.x + b.x + c.x + d.x, a.y + b.y + c.y + d.y,
                a.z + b.z + c.z + d.z, a.w + b.w + c.w + d.w};
    *(float4*)(C + i) = o;
}

// XCD-aware bijective block swizzle (requires nwg % 8 == 0, else identity):
// consecutive dispatch ids (same XCD via %8 round-robin) get contiguous tile
// ranges -> row-panel A-tiles reused within one XCD L2.
__device__ __forceinline__ void xcd_tile(int& bx, int& by) {
    int nbx = gridDim.x, nby = gridDim.y;
    int nwg = nbx * nby;
    int flat = by * nbx + bx;
    if (!(nwg & 7)) {
        int sw = (flat & 7) * (nwg >> 3) + (flat >> 3);
        bx = sw % nbx;
        by = sw / nbx;
    }
}

// ---------------------------------------------------------------------------
// Split-bf16 MFMA GEMM for the selection-critical z path:
//   z = keys @ Amat + bz, computed as Khi@Ahi + Khi@Alo + Klo@Ahi
// (each split half bf16; ~17 effective mantissa bits; lo*lo term ~2^-18 dropped).
// Writes OUTPUT TRANSPOSED: zT[b][c][t], m = b*LEN + t.
// ---------------------------------------------------------------------------
__global__ __launch_bounds__(256) void gemm_split_zT(
    const unsigned short* __restrict__ Khi, const unsigned short* __restrict__ Klo,
    const unsigned short* __restrict__ AhiT, const unsigned short* __restrict__ AloT,
    const float* __restrict__ bias, float* __restrict__ zT, int M, int N, int K)
{
    __shared__ unsigned short Ah[128 * 32];
    __shared__ unsigned short Al[128 * 32];
    __shared__ unsigned short Bh[128 * 32];
    __shared__ unsigned short Bl[128 * 32];
    const int tid = threadIdx.x;
    const int lane = tid & 63;
    const int wv = tid >> 6;
    const int wm = wv >> 1, wn = wv & 1;
    const int l16 = lane & 15, quad = lane >> 4;
    int bx = blockIdx.x, by = blockIdx.y;
    xcd_tile(bx, by);
    const size_t m0 = (size_t)by * 128;
    const size_t n0 = (size_t)bx * 128;

    const int s0 = tid, s1 = tid + 256;       // segment: row = s>>2, col8 = s&3
    const size_t oA0 = (m0 + (s0 >> 2)) * (size_t)K + (s0 & 3) * 8;
    const size_t oA1 = (m0 + (s1 >> 2)) * (size_t)K + (s1 & 3) * 8;
    const size_t oB0 = (n0 + (s0 >> 2)) * (size_t)K + (s0 & 3) * 8;
    const size_t oB1 = (n0 + (s1 >> 2)) * (size_t)K + (s1 & 3) * 8;

    f32x4 acc[4][4];
#pragma unroll
    for (int i = 0; i < 4; i++)
#pragma unroll
        for (int j = 0; j < 4; j++) acc[i][j] = (f32x4){0.f, 0.f, 0.f, 0.f};

    for (int k0 = 0; k0 < K; k0 += 32) {
        __syncthreads();
        gl_lds16(Khi + oA0 + k0, &Ah[s0 * 8]);
        gl_lds16(Khi + oA1 + k0, &Ah[s1 * 8]);
        gl_lds16(Klo + oA0 + k0, &Al[s0 * 8]);
        gl_lds16(Klo + oA1 + k0, &Al[s1 * 8]);
        gl_lds16(AhiT + oB0 + k0, &Bh[s0 * 8]);
        gl_lds16(AhiT + oB1 + k0, &Bh[s1 * 8]);
        gl_lds16(AloT + oB0 + k0, &Bl[s0 * 8]);
        gl_lds16(AloT + oB1 + k0, &Bl[s1 * 8]);
        __syncthreads();
        short8 ah[4], al[4], bh[4], bl[4];
#pragma unroll
        for (int mi = 0; mi < 4; mi++) {
            int off = (wm * 64 + mi * 16 + l16) * 32 + quad * 8;
            ah[mi] = *(const short8*)&Ah[off];
            al[mi] = *(const short8*)&Al[off];
        }
#pragma unroll
        for (int ni = 0; ni < 4; ni++) {
            int off = (wn * 64 + ni * 16 + l16) * 32 + quad * 8;
            bh[ni] = *(const short8*)&Bh[off];
            bl[ni] = *(const short8*)&Bl[off];
        }
#pragma unroll
        for (int mi = 0; mi < 4; mi++)
#pragma unroll
            for (int ni = 0; ni < 4; ni++) {
                acc[mi][ni] = __builtin_amdgcn_mfma_f32_16x16x32_bf16(
                    ah[mi], bh[ni], acc[mi][ni], 0, 0, 0);
                acc[mi][ni] = __builtin_amdgcn_mfma_f32_16x16x32_bf16(
                    ah[mi], bl[ni], acc[mi][ni], 0, 0, 0);
                acc[mi][ni] = __builtin_amdgcn_mfma_f32_16x16x32_bf16(
                    al[mi], bh[ni], acc[mi][ni], 0, 0, 0);
            }
    }

    const int b = (int)(m0 / LEN);
    const int t0 = (int)(m0 % LEN);
#pragma unroll
    for (int mi = 0; mi < 4; mi++) {
#pragma unroll
        for (int ni = 0; ni < 4; ni++) {
            int c = (int)n0 + wn * 64 + ni * 16 + l16;
            int t = t0 + wm * 64 + mi * 16 + quad * 4;
            float bb = bias[c];
            float* zp = zT + ((size_t)b * DM + c) * LEN + t;
#pragma unroll
            for (int r = 0; r < 4; r++) zp[r] = acc[mi][ni][r] + bb;
        }
    }
}

// ---------------------------------------------------------------------------
// bf16 MFMA GEMM (m97 structure): C[M,N] = A[M,K] * Bt[N,K]^T + bias.
// cmode: 0 -> f32 C, 1 -> bf16 C.
// ---------------------------------------------------------------------------
__global__ __launch_bounds__(256) void gemm_bf16(const unsigned short* __restrict__ A,
    const unsigned short* __restrict__ Bt, const float* __restrict__ bias,
    void* __restrict__ C, int M, int N, int K, int cmode)
{
    __shared__ unsigned short As[128 * 32];
    __shared__ unsigned short Bs[128 * 32];
    const int tid = threadIdx.x;
    const int lane = tid & 63;
    const int wv = tid >> 6;
    const int wm = wv >> 1, wn = wv & 1;
    const int l16 = lane & 15, quad = lane >> 4;
    int bx = blockIdx.x, by = blockIdx.y;
    xcd_tile(bx, by);
    const size_t m0 = (size_t)by * 128;
    const size_t n0 = (size_t)bx * 128;

    const int s0 = tid, s1 = tid + 256;
    const unsigned short* gA0 = A + (m0 + (s0 >> 2)) * (size_t)K + (s0 & 3) * 8;
    const unsigned short* gA1 = A + (m0 + (s1 >> 2)) * (size_t)K + (s1 & 3) * 8;
    const unsigned short* gB0 = Bt + (n0 + (s0 >> 2)) * (size_t)K + (s0 & 3) * 8;
    const unsigned short* gB1 = Bt + (n0 + (s1 >> 2)) * (size_t)K + (s1 & 3) * 8;
    unsigned short* lA0 = &As[s0 * 8];
    unsigned short* lA1 = &As[s1 * 8];
    unsigned short* lB0 = &Bs[s0 * 8];
    unsigned short* lB1 = &Bs[s1 * 8];

    f32x4 acc[4][4];
#pragma unroll
    for (int i = 0; i < 4; i++)
#pragma unroll
        for (int j = 0; j < 4; j++) acc[i][j] = (f32x4){0.f, 0.f, 0.f, 0.f};

    for (int k0 = 0; k0 < K; k0 += 32) {
        __syncthreads();
        gl_lds16(gA0 + k0, lA0);
        gl_lds16(gA1 + k0, lA1);
        gl_lds16(gB0 + k0, lB0);
        gl_lds16(gB1 + k0, lB1);
        __syncthreads();
        short8 af[4], bf[4];
#pragma unroll
        for (int mi = 0; mi < 4; mi++)
            af[mi] = *(const short8*)&As[(wm * 64 + mi * 16 + l16) * 32 + quad * 8];
#pragma unroll
        for (int ni = 0; ni < 4; ni++)
            bf[ni] = *(const short8*)&Bs[(wn * 64 + ni * 16 + l16) * 32 + quad * 8];
#pragma unroll
        for (int mi = 0; mi < 4; mi++)
#pragma unroll
            for (int ni = 0; ni < 4; ni++)
                acc[mi][ni] = __builtin_amdgcn_mfma_f32_16x16x32_bf16(
                    af[mi], bf[ni], acc[mi][ni], 0, 0, 0);
    }

#pragma unroll
    for (int mi = 0; mi < 4; mi++) {
#pragma unroll
        for (int ni = 0; ni < 4; ni++) {
            int gm = (int)m0 + wm * 64 + mi * 16 + quad * 4;
            int gn = (int)n0 + wn * 64 + ni * 16 + l16;
            float bb = bias ? bias[gn] : 0.f;
#pragma unroll
            for (int r = 0; r < 4; r++) {
                float v = acc[mi][ni][r] + bb;
                if (cmode == 0)
                    ((float*)C)[(size_t)(gm + r) * N + gn] = v;
                else
                    ((unsigned short*)C)[(size_t)(gm + r) * N + gn] = f2bf(v);
            }
        }
    }
}

// ---------------------------------------------------------------------------
// [B, L, D] f32 -> [B, D, L] f32 transpose (queries)
// ---------------------------------------------------------------------------
__global__ __launch_bounds__(256) void transpose_bld(const float* __restrict__ in,
                                                     float* __restrict__ out)
{
    __shared__ float tile[32][33];
    int b = blockIdx.z;
    int d0 = blockIdx.x * 32, t0 = blockIdx.y * 32;
    int tx = threadIdx.x & 31, ty = threadIdx.x >> 5;
    const float* ip = in + (size_t)b * LEN * DM;
    float* op = out + (size_t)b * DM * LEN;
#pragma unroll
    for (int r = 0; r < 4; r++)
        tile[ty * 4 + r][tx] = ip[(size_t)(t0 + ty * 4 + r) * DM + d0 + tx];
    __syncthreads();
#pragma unroll
    for (int r = 0; r < 4; r++)
        op[(size_t)(d0 + ty * 4 + r) * LEN + t0 + tx] = tile[tx][ty * 4 + r];
}

// 1024x1024 f32 transpose (Wq -> WqT)
__global__ __launch_bounds__(256) void transpose_1024(const float* __restrict__ in,
                                                      float* __restrict__ out)
{
    __shared__ float tile[32][33];
    int bx = blockIdx.x & 31, by = blockIdx.x >> 5;
    int tx = threadIdx.x & 31, tq = threadIdx.x >> 5;
#pragma unroll
    for (int r = 0; r < 4; r++)
        tile[tq * 4 + r][tx] = in[(size_t)(by * 32 + tq * 4 + r) * 1024 + bx * 32 + tx];
    __syncthreads();
#pragma unroll
    for (int r = 0; r < 4; r++)
        out[(size_t)(bx * 32 + tq * 4 + r) * 1024 + by * 32 + tx] = tile[tx][tq * 4 + r];
}

// 1024x1024 f32 W[K][N] -> bf16 WT[N][K]
__global__ __launch_bounds__(256) void transpose_w_bf16(const float* __restrict__ in,
                                                        unsigned short* __restrict__ out)
{
    __shared__ float tile[32][33];
    int bx = blockIdx.x & 31, by = blockIdx.x >> 5;
    int tx = threadIdx.x & 31, tq = threadIdx.x >> 5;
#pragma unroll
    for (int r = 0; r < 4; r++)
        tile[tq * 4 + r][tx] = in[(size_t)(by * 32 + tq * 4 + r) * 1024 + bx * 32 + tx];
    __syncthreads();
#pragma unroll
    for (int r = 0; r < 4; r++)
        out[(size_t)(bx * 32 + tq * 4 + r) * 1024 + by * 32 + tx] = f2bf(tile[tx][tq * 4 + r]);
}

// 1024x1024 f32 W[K][N] -> split bf16 hi/lo, transposed [N][K]
__global__ __launch_bounds__(256) void transpose_w_split(const float* __restrict__ in,
    unsigned short* __restrict__ hi, unsigned short* __restrict__ lo)
{
    __shared__ float tile[32][33];
    int bx = blockIdx.x & 31, by = blockIdx.x >> 5;
    int tx = threadIdx.x & 31, tq = threadIdx.x >> 5;
#pragma unroll
    for (int r = 0; r < 4; r++)
        tile[tq * 4 + r][tx] = in[(size_t)(by * 32 + tq * 4 + r) * 1024 + bx * 32 + tx];
    __syncthreads();
#pragma unroll
    for (int r = 0; r < 4; r++) {
        float x = tile[tx][tq * 4 + r];
        unsigned short h = f2bf(x);
        unsigned short l = f2bf(x - bf2f(h));
        size_t o = (size_t)(bx * 32 + tq * 4 + r) * 1024 + by * 32 + tx;
        hi[o] = h; lo[o] = l;
    }
}

// f32 -> split bf16 hi/lo elementwise (n multiple of 4)
__global__ __launch_bounds__(256) void split_bf16(const float* __restrict__ in,
    unsigned short* __restrict__ hi, unsigned short* __restrict__ lo, size_t n)
{
    size_t i = ((size_t)blockIdx.x * 256 + threadIdx.x) * 4;
    if (i >= n) return;
    float4 v = *(const float4*)(in + i);
    ushort4 h, l;
    h.x = f2bf(v.x); l.x = f2bf(v.x - bf2f(h.x));
    h.y = f2bf(v.y); l.y = f2bf(v.y - bf2f(h.y));
    h.z = f2bf(v.z); l.z = f2bf(v.z - bf2f(h.z));
    h.w = f2bf(v.w); l.w = f2bf(v.w - bf2f(h.w));
    *(ushort4*)(hi + i) = h;
    *(ushort4*)(lo + i) = l;
}

// f32 -> bf16 elementwise (n multiple of 4)
__global__ __launch_bounds__(256) void conv_bf16(const float* __restrict__ in,
                                                 unsigned short* __restrict__ out, size_t n)
{
    size_t i = ((size_t)blockIdx.x * 256 + threadIdx.x) * 4;
    if (i >= n) return;
    float4 v = *(const float4*)(in + i);
    ushort4 o;
    o.x = f2bf(v.x); o.y = f2bf(v.y); o.z = f2bf(v.z); o.w = f2bf(v.w);
    *(ushort4*)(out + i) = o;
}

// bz[j] = sum_d bk[d] * WqT[d,j]
__global__ __launch_bounds__(256) void bz_kernel(const float* __restrict__ bk,
    const float* __restrict__ WqT, float* __restrict__ bz)
{
    int j = blockIdx.x * 256 + threadIdx.x;
    float s = 0.f;
    for (int d = 0; d < 1024; d++) s = fmaf(bk[d], WqT[(size_t)d * 1024 + j], s);
    bz[j] = s;
}

// ---------------------------------------------------------------------------
// 3072-point complex FFT in LDS, fused radix-4 Stockham (5 double-stages) on
// 3x1024 sub-FFTs + radix-3 combine. Interleaved float2 storage (b64 LDS ops),
// XOR bank swizzle swz(i) = i ^ ((i>>4)&15). All twiddles in registers
// (tid-only dependent; w2 = wA^2 exactly). LDS = bufA+bufB = 48 KiB.
// Result ends in bufA.
// ---------------------------------------------------------------------------
__device__ __forceinline__ int swz(int i) { return i ^ ((i >> 4) & 15); }

__device__ __forceinline__ float2 cmul(float2 a, float2 b) {
    return make_float2(a.x * b.x - a.y * b.y, a.x * b.y + a.y * b.x);
}

struct TwRegs {
    float2 wA[5], w2[5], w1[4], w2c[4];
};

__device__ __forceinline__ void make_tw(TwRegs& T, int tid)
{
    const float TWO_PI = 6.28318530717958647692f;
#pragma unroll
    for (int si = 0; si < 5; si++) {
        int s = si * 2;
        int a = (tid >> s) << s;
        float sv, cv; sincosf(-TWO_PI * (float)a / 1024.f, &sv, &cv);
        T.wA[si] = make_float2(cv, sv);
        T.w2[si] = make_float2(cv * cv - sv * sv, 2.f * cv * sv);
    }
#pragma unroll
    for (int j = 0; j < 4; j++) {
        int k2 = tid + (j << 8);
        float sv, cv; sincosf(-TWO_PI * (float)k2 / 3072.f, &sv, &cv);
        T.w1[j] = make_float2(cv, sv);
        T.w2c[j] = make_float2(cv * cv - sv * sv, 2.f * cv * sv);
    }
}

__device__ __forceinline__ void fft3072_r4(float2* __restrict__ bufA,
                                           float2* __restrict__ bufB,
                                           const TwRegs& T, int tid)
{
    float2* src = bufA;
    float2* dst = bufB;
#pragma unroll
    for (int s = 0; s < 10; s += 2) {
        const int st = 1 << s;
        const int q = tid & (st - 1);
        const int p = tid >> s;
        const float2 wA = T.wA[s >> 1];
        const float2 w2 = T.w2[s >> 1];
        const int io = q + (p << (s + 2));
#pragma unroll
        for (int k = 0; k < 3; k++) {
            const int base = k << 10;
            float2 a1 = src[swz(base + tid)];
            float2 a2 = src[swz(base + tid + 256)];
            float2 b1 = src[swz(base + tid + 512)];
            float2 b2 = src[swz(base + tid + 768)];
            float2 uA0 = make_float2(a1.x + b1.x, a1.y + b1.y);
            float2 d1  = make_float2(a1.x - b1.x, a1.y - b1.y);
            float2 uA1 = cmul(d1, wA);
            float2 uB0 = make_float2(a2.x + b2.x, a2.y + b2.y);
            float2 d2  = make_float2(a2.x - b2.x, a2.y - b2.y);
            float2 e   = cmul(d2, wA);
            float2 uB1 = make_float2(e.y, -e.x);          // e * (-i)
            float2 o0 = make_float2(uA0.x + uB0.x, uA0.y + uB0.y);
            float2 o1 = make_float2(uA1.x + uB1.x, uA1.y + uB1.y);
            float2 e2 = make_float2(uA0.x - uB0.x, uA0.y - uB0.y);
            float2 e3 = make_float2(uA1.x - uB1.x, uA1.y - uB1.y);
            dst[swz(base + io)] = o0;
            dst[swz(base + io + st)] = o1;
            dst[swz(base + io + 2 * st)] = cmul(e2, w2);
            dst[swz(base + io + 3 * st)] = cmul(e3, w2);
        }
        __syncthreads();
        float2* t = src; src = dst; dst = t;
    }
    // radix-3 combine: src == bufB here, dst == bufA
    const float OMR = -0.5f, OMI = -0.86602540378443864676f;
#pragma unroll
    for (int j = 0; j < 4; j++) {
        int k2 = tid + (j << 8);
        float2 y0 = src[swz(k2)];
        float2 y1 = src[swz(1024 + k2)];
        float2 y2 = src[swz(2048 + k2)];
        float2 w1 = T.w1[j];
        float2 w2c = T.w2c[j];
        float2 u1 = cmul(y1, w1);
        float2 u2 = cmul(y2, w2c);
        dst[swz(k2)] = make_float2(y0.x + u1.x + u2.x, y0.y + u1.y + u2.y);
        dst[swz(1024 + k2)] = make_float2(
            y0.x + (OMR * u1.x - OMI * u1.y) + (OMR * u2.x + OMI * u2.y),
            y0.y + (OMR * u1.y + OMI * u1.x) + (OMR * u2.y - OMI * u2.x));
        dst[swz(2048 + k2)] = make_float2(
            y0.x + (OMR * u1.x + OMI * u1.y) + (OMR * u2.x - OMI * u2.y),
            y0.y + (OMR * u1.y - OMI * u1.x) + (OMR * u2.y + OMI * u2.x));
    }
    __syncthreads();
}

// ---------------------------------------------------------------------------
// Per (batch, 16-channel group): inputs channel-major [B, D, L] (coalesced).
// Pack w = q + i*z, FFT, P[f] = Qf * conj(Zf). q,z real => cross-spectrum is
// Hermitian: accumulate only f in [0,1536]. NO atomics: each block writes a
// private partial slab (coalesced); reduce_S sums the 64 slabs per batch.
// T14 prefetch: next channel's 24 loads issued before the current FFT.
// ---------------------------------------------------------------------------
#define SLAB 3104   // floats per partial slab (3074 used, 64B-multiple stride)

__global__ __launch_bounds__(256) void fft_corr(const float* __restrict__ qT,
    const float* __restrict__ zT, float* __restrict__ Spart)
{
    __shared__ float2 bufA[3072], bufB[3072];
    const int tid = threadIdx.x;
    const int b = blockIdx.x >> 6;
    const int c0 = (blockIdx.x & 63) << 4;
    TwRegs T;
    make_tw(T, tid);
    float pR[6], pI[6];
#pragma unroll
    for (int j = 0; j < 6; j++) { pR[j] = 0.f; pI[j] = 0.f; }
    float eR = 0.f, eI = 0.f;   // f = 1536 (tid 0 only)

    const float* qp = qT + ((size_t)b * DM + c0) * LEN;
    const float* zp = zT + ((size_t)b * DM + c0) * LEN;
    float qv[12], zv[12];
#pragma unroll
    for (int j = 0; j < 12; j++) {
        int t = tid + (j << 8);
        qv[j] = qp[t]; zv[j] = zp[t];
    }

    for (int ci = 0; ci < 16; ci++) {
        // pack current channel's registers into LDS
#pragma unroll
        for (int j = 0; j < 12; j++) {
            int t = tid + (j << 8);
            int t1 = t % 3, t2 = t / 3;
            bufA[swz(t1 * 1024 + t2)] = make_float2(qv[j], zv[j]);
        }
        // T14: issue next channel's loads now; they complete under the FFT
        if (ci < 15) {
            const float* qn = qp + (size_t)(ci + 1) * LEN;
            const float* zn = zp + (size_t)(ci + 1) * LEN;
#pragma unroll
            for (int j = 0; j < 12; j++) {
                int t = tid + (j << 8);
                qv[j] = qn[t]; zv[j] = zn[t];
            }
        }
        __syncthreads();
        fft3072_r4(bufA, bufB, T, tid);
        // result in bufA; accumulate f in [0,1535] + self-conjugate f=1536
#pragma unroll
        for (int j = 0; j < 6; j++) {
            int f = tid + (j << 8);
            int fc = (f == 0) ? 0 : 3072 - f;
            float2 Wf = bufA[swz(f)];
            float2 Wc = bufA[swz(fc)];
            float WcI = -Wc.y;
            float qR = 0.5f * (Wf.x + Wc.x), qI = 0.5f * (Wf.y + WcI);
            float dR = Wf.x - Wc.x, dI = Wf.y - WcI;
            float zR = 0.5f * dI, zI = -0.5f * dR;
            pR[j] += qR * zR + qI * zI;
            pI[j] += qI * zR - qR * zI;
        }
        if (tid == 0) {
            float2 Wf = bufA[swz(1536)];
            eR += Wf.x * Wf.y;    // qR * zR with qR=Wf.x, zR=Wf.y (dI=2*Wf.y)
        }
        __syncthreads();
    }
    // coalesced private-slab store (float2 per bin), zero contention
    float2* Pb = (float2*)(Spart + (size_t)blockIdx.x * SLAB);
#pragma unroll
    for (int j = 0; j < 6; j++) {
        int f = tid + (j << 8);
        Pb[f] = make_float2(pR[j], pI[j]);
    }
    if (tid == 0) Pb[1536] = make_float2(eR, eI);
}

// S[b][f] = sum over the batch's 64 slabs, f in [0,1536] (r = f*2+comp)
__global__ __launch_bounds__(256) void reduce_S(const float* __restrict__ Spart,
                                                float* __restrict__ S)
{
    int g = blockIdx.x * 256 + threadIdx.x;
    if (g >= BSZ * 3074) return;
    int b = g / 3074, r = g - b * 3074;
    const float* p = Spart + (size_t)(b * 64) * SLAB + r;
    float s = 0.f;
#pragma unroll 8
    for (int k = 0; k < 64; k++) s += p[(size_t)k * SLAB];
    S[(size_t)b * 6144 + r] = s;
}

__global__ __launch_bounds__(256) void ifft_mean(const float* __restrict__ S,
                                                 float* __restrict__ mv)
{
    __shared__ float2 bufA[3072], bufB[3072];
    const int tid = threadIdx.x;
    const int b = blockIdx.x;
    TwRegs T;
    make_tw(T, tid);
    // S stored only for f in [0,1536]; reconstruct f>1536 via S_{-f}=conj(S_f).
    for (int t = tid; t < 3072; t += 256) {
        int tt = (t <= 1536) ? t : 3072 - t;
        float sR = S[((size_t)b * 3072 + tt) * 2 + 0];
        float sI = S[((size_t)b * 3072 + tt) * 2 + 1];
        float im = (t > 1536) ? sI : -sI;   // conj-pack for inverse FFT
        int t1 = t % 3, t2 = t / 3;
        bufA[swz(t1 * 1024 + t2)] = make_float2(sR, im);
    }
    __syncthreads();
    fft3072_r4(bufA, bufB, T, tid);
    const float scale = 1.f / (3072.f * 1024.f);
    for (int t = tid; t < 3072; t += 256)
        mv[(size_t)b * 3072 + t] = bufA[swz(t)].x * scale;
}

__global__ __launch_bounds__(256) void topk_softmax(const float* __restrict__ mv,
    float* __restrict__ wout, int* __restrict__ dout)
{
    const int b = blockIdx.x, tid = threadIdx.x;
    __shared__ float v[3072];
    __shared__ float rv[256];
    __shared__ int   ri[256];
    __shared__ float topv[TOPK];
    __shared__ int   topi[TOPK];
    for (int t = tid; t < 3072; t += 256) v[t] = mv[(size_t)b * 3072 + t];
    __syncthreads();
    for (int it = 0; it < TOPK; it++) {
        float best = -3.0e38f; int bi = 0;
        for (int t = tid; t < 3072; t += 256) {
            float x = v[t];
            if (x > best) { best = x; bi = t; }
        }
        rv[tid] = best; ri[tid] = bi;
        __syncthreads();
        for (int off = 128; off > 0; off >>= 1) {
            if (tid < off) {
                float ov = rv[tid + off]; int oi = ri[tid + off];
                if (ov > rv[tid] || (ov == rv[tid] && oi < ri[tid])) {
                    rv[tid] = ov; ri[tid] = oi;
                }
            }
            __syncthreads();
        }
        if (tid == 0) { topv[it] = rv[0]; topi[it] = ri[0]; v[ri[0]] = -3.0e38f; }
        __syncthreads();
    }
    if (tid == 0) {
        float m = topv[0];
        float e[TOPK]; float ssum = 0.f;
        for (int i = 0; i < TOPK; i++) { e[i] = expf(topv[i] - m); ssum += e[i]; }
        for (int i = 0; i < TOPK; i++) {
            wout[b * TOPK + i] = e[i] / ssum;
            dout[b * TOPK + i] = topi[i];
        }
    }
}

// agg[b,t,c] = sum_i w[b,i] * V[b,(t+d[b,i])%L,c]   (bf16 in, bf16 out)
__global__ __launch_bounds__(256) void agg_bf16(const unsigned short* __restrict__ V,
    const float* __restrict__ w, const int* __restrict__ d,
    unsigned short* __restrict__ agg)
{
    size_t gid = (size_t)blockIdx.x * 256 + threadIdx.x;   // 8-channel chunk index
    int c8 = (int)(gid & 127);
    size_t rest = gid >> 7;
    int t = (int)(rest % LEN);
    int b = (int)(rest / LEN);
    float acc[8];
#pragma unroll
    for (int j = 0; j < 8; j++) acc[j] = 0.f;
#pragma unroll
    for (int i = 0; i < TOPK; i++) {
        float wi = w[b * TOPK + i];
        int r = t + d[b * TOPK + i];
        if (r >= LEN) r -= LEN;
        const unsigned short* vp = V + ((size_t)b * LEN + r) * DM + c8 * 8;
        uint4 raw = *(const uint4*)vp;
        unsigned int uu[4] = {raw.x, raw.y, raw.z, raw.w};
#pragma unroll
        for (int k = 0; k < 4; k++) {
            acc[2 * k]     = fmaf(wi, bf2f((unsigned short)(uu[k] & 0xffff)), acc[2 * k]);
            acc[2 * k + 1] = fmaf(wi, bf2f((unsigned short)(uu[k] >> 16)), acc[2 * k + 1]);
        }
    }
    unsigned int ou[4];
#pragma unroll
    for (int k = 0; k < 4; k++)
        ou[k] = (unsigned int)f2bf(acc[2 * k]) | ((unsigned int)f2bf(acc[2 * k + 1]) << 16);
    uint4 o = {ou[0], ou[1], ou[2], ou[3]};
    *(uint4*)(agg + gid * 8) = o;
}

// ---------------------------------------------------------------------------
extern "C" void kernel_launch(void* const* d_in, const int* in_sizes, int n_in,
                              void* d_out, int out_size, void* d_ws, size_t ws_size,
                              hipStream_t stream)
{
    const float* queries = (const float*)d_in[0];
    const float* keys    = (const float*)d_in[1];
    const float* values  = (const float*)d_in[2];
    const float* Wq = (const float*)d_in[3];
    // bq: tau-constant in mean_value -> topk/softmax invariant; legally dropped
    const float* Wk = (const float*)d_in[5];
    const float* bk = (const float*)d_in[6];
    const float* Wv = (const float*)d_in[7];
    const float* bv = (const float*)d_in[8];
    const float* Wo = (const float*)d_in[9];
    const float* bo = (const float*)d_in[10];
    float* out = (float*)d_out;

    char* ws = (char*)d_ws;
    size_t off = 0;
    auto alloc = [&](size_t bytes) -> char* {
        char* p = ws + off;
        off += (bytes + 255) & ~(size_t)255;
        return p;
    };
    const size_t BLD = (size_t)BSZ * LEN * DM;          // 25165824 elements
    float* WqT  = (float*)alloc((size_t)1024 * 1024 * 4);
    float* Amat = (float*)alloc((size_t)1024 * 1024 * 4);
    unsigned short* AhiT = (unsigned short*)alloc((size_t)1024 * 1024 * 2);
    unsigned short* AloT = (unsigned short*)alloc((size_t)1024 * 1024 * 2);
    float* bz   = (float*)alloc(1024 * 4);
    float* S    = (float*)alloc((size_t)BSZ * 3072 * 2 * 4);
    float* mv   = (float*)alloc((size_t)BSZ * 3072 * 4);
    float* wsm  = (float*)alloc(BSZ * TOPK * 4);
    int*   dly  = (int*)alloc(BSZ * TOPK * 4);
    unsigned short* WvT = (unsigned short*)alloc((size_t)1024 * 1024 * 2);
    unsigned short* WoT = (unsigned short*)alloc((size_t)1024 * 1024 * 2);
    // two big regions, phase-aliased:
    //   bigA: ph0: khi+klo (bf16) | ph1: qT f32 | ph2: vb16 + aggb (bf16)
    //   bigB: ph-1: Amat split-K partials (4x4MB) | ph1: zT f32 | ph2: Vb bf16
    char* bigA = alloc(BLD * 4);
    char* bigB = alloc(BLD * 4);
    unsigned short* khi = (unsigned short*)bigA;
    unsigned short* klo = (unsigned short*)(bigA + BLD * 2);
    float* qT = (float*)bigA;
    float* zT = (float*)bigB;
    float* Apart = (float*)bigB;            // 4 x 1024^2 f32 partials (16 MB)
    unsigned short* vb16 = (unsigned short*)bigA;
    unsigned short* aggb = (unsigned short*)(bigA + BLD * 2);
    unsigned short* Vb   = (unsigned short*)bigB;
    // fft partial slabs: 512 x SLAB floats = 6.36 MB, aliased onto WqT+Amat
    // (both dead before fft_corr; contiguous 8 MB region)
    float* Spart = WqT;

    const int BL = BSZ * LEN; // 24576

    // ---- selection path (split-bf16 MFMA; ~17 mantissa bits) ----
    transpose_1024<<<1024, 256, 0, stream>>>(Wq, WqT);
    gemm_f32_sk<<<dim3(8, 8, 4), 256, 0, stream>>>(Wk, WqT, Apart, 1024, 1024, 1024);
    reduce4_f32<<<1024, 256, 0, stream>>>(Apart, Amat, 1024 * 1024);
    bz_kernel<<<4, 256, 0, stream>>>(bk, WqT, bz);
    transpose_w_split<<<1024, 256, 0, stream>>>(Amat, AhiT, AloT);
    split_bf16<<<(int)((BLD / 4 + 255) / 256), 256, 0, stream>>>(keys, khi, klo, BLD);
    // zT[b][c][t] = (keys @ Amat + bz)^T  via 3-product split-bf16 MFMA
    gemm_split_zT<<<dim3(8, 192), 256, 0, stream>>>(khi, klo, AhiT, AloT, bz, zT,
                                                    BL, 1024, 1024);
    // qT[b][c][t]  (khi/klo dead now; overwrite bigA)
    transpose_bld<<<dim3(32, 96, 8), 256, 0, stream>>>(queries, qT);
    fft_corr<<<BSZ * 64, 256, 0, stream>>>(qT, zT, Spart);
    reduce_S<<<(BSZ * 3074 + 255) / 256, 256, 0, stream>>>(Spart, S);
    ifft_mean<<<BSZ, 256, 0, stream>>>(S, mv);
    topk_softmax<<<BSZ, 256, 0, stream>>>(mv, wsm, dly);

    // ---- value path (bf16 MFMA) ----
    conv_bf16<<<(int)((BLD / 4 + 255) / 256), 256, 0, stream>>>(values, vb16, BLD);
    transpose_w_bf16<<<1024, 256, 0, stream>>>(Wv, WvT);
    transpose_w_bf16<<<1024, 256, 0, stream>>>(Wo, WoT);
    gemm_bf16<<<dim3(8, 192), 256, 0, stream>>>(vb16, WvT, bv, Vb, BL, 1024, 1024, 1);
    agg_bf16<<<(int)(((size_t)BL * 128) / 256), 256, 0, stream>>>(Vb, wsm, dly, aggb);
    gemm_bf16<<<dim3(8, 192), 256, 0, stream>>>(aggb, WoT, bo, out, BL, 1024, 1024, 0);
}